// Round 14
// baseline (251.777 us; speedup 1.0000x reference)
//
#include <hip/hip_runtime.h>
#include <hip/hip_bf16.h>
#include <stdint.h>

// Problem constants
#define BB     8
#define CC     128
#define HW     9216      // 96*96
#define NHEAD  8
#define HD     64
#define NCH    16        // gram n-chunks
#define CHUNK  576       // HW/NCH
#define KPAD   68        // gram LDS row (ushort): 64 px + 4 pad = 136B stride
#define VTPAD  68        // k3 v^T LDS row (ushort): 64 e + 4 pad = 136B stride

typedef __hip_bfloat16 bf16;
using frag16 = __attribute__((ext_vector_type(8))) short;  // 8 bf16 (4 VGPRs)
using f32x4  = __attribute__((ext_vector_type(4))) float;

__device__ __forceinline__ float b2f(bf16 v) { return __bfloat162float(v); }
__device__ __forceinline__ bf16  f2b(float v) { return __float2bfloat16(v); }

__device__ __forceinline__ float lo2f(unsigned int u) {
  union { unsigned int i; float f; } c; c.i = u << 16; return c.f;
}
__device__ __forceinline__ float hi2f(unsigned int u) {
  union { unsigned int i; float f; } c; c.i = u & 0xffff0000u; return c.f;
}

__device__ __forceinline__ unsigned int pack2(float a, float b) {
  union { __hip_bfloat162 h2; unsigned int u; } c;
  c.h2 = __float22bfloat162_rn(make_float2(a, b));   // v_cvt_pk_bf16_f32
  return c.u;
}

// LDS frag read from 8B-aligned address
__device__ __forceinline__ frag16 ldsfrag(const unsigned short* p) {
  uint2 lo = *(const uint2*)p;
  uint2 hi = *(const uint2*)(p + 4);
  union { unsigned int u[4]; frag16 f; } c;
  c.u[0] = lo.x; c.u[1] = lo.y; c.u[2] = hi.x; c.u[3] = hi.y;
  return c.f;
}
// LDS 16B store as two 8B stores (8B-aligned dst)
__device__ __forceinline__ void ldsst(unsigned short* p, uint4 v) {
  *(uint2*)p = make_uint2(v.x, v.y);
  *(uint2*)(p + 4) = make_uint2(v.z, v.w);
}

// Shared staging for k1: zero-pad halo only (interior fully overwritten), then stage plane.
__device__ __forceinline__ void stage_plane(float* xs, const float* xp, int tid) {
  const float4 z4 = make_float4(0.f, 0.f, 0.f, 0.f);
  for (int i = tid; i < 98; i += 256) *(float4*)&xs[i * 100] = z4;        // cols 0..3
  for (int i = tid; i < 24; i += 256) *(float4*)&xs[4 + i * 4] = z4;     // row 0
  for (int i = tid; i < 25; i += 256) *(float4*)&xs[9704 + i * 4] = z4;  // row 97 + guard
  for (int i = tid; i < 96 * 24; i += 256) {
    int y = i / 24, g4 = i - y * 24;
    ((float4*)(xs + (y + 1) * 100 + 4))[g4] = ((const float4*)(xp + y * 96))[g4];
  }
}

// ---------------------------------------------------------------- K1: qkv depthwise conv + q/k norms
// block = (b, c), full 96x96 plane in LDS. Split 2x512 (b_base) this round for
// observability: exposes gram/k3/k4 in top-5 with counters (~12us rent).
__global__ __launch_bounds__(256) void k1_qkv(
    const float* __restrict__ x, const float* __restrict__ wq,
    const float* __restrict__ bq,
    bf16* __restrict__ qg, bf16* __restrict__ kg, bf16* __restrict__ vg,
    float* __restrict__ qn2, float* __restrict__ kn2, int b_base) {
  __shared__ float xs[98 * 100 + 4];
  __shared__ float red[32];
  int tid = threadIdx.x;
  int wave = tid >> 6, lane = tid & 63;
  int b = b_base + (blockIdx.x >> 7), c = blockIdx.x & 127;
  const float* xp = x + (size_t)(b * CC + c) * HW;
  stage_plane(xs, xp, tid);
  __syncthreads();

  int half = c >> 6, d = c & 63;
  int nidx[8];
  size_t basep[12];
#pragma unroll
  for (int j = 0; j < 12; ++j) {
    int e = j & 3;
    int h = e * 2 + half;
    int ni = (b * NHEAD + h) * HD + d;
    if (j < 8) nidx[j] = ni;
    basep[j] = (size_t)ni * HW;
  }
  const float* wrow = wq + c * 108;
  const float* brow = bq + c * 12;

  float ssq[8];
#pragma unroll
  for (int j = 0; j < 8; ++j) ssq[j] = 0.f;

#pragma unroll 1
  for (int it = 0; it < 5; ++it) {
    int u = it * 256 + tid;
    if (u < 1152) {
      int ly = u / 12;
      int x8 = (u - ly * 12) * 8;
      int p0 = ly * 96 + x8;
      float w10[3][10];
#pragma unroll
      for (int ky = 0; ky < 3; ++ky) {
        int basea = (ly + ky) * 100 + 4 + x8;
        float4 M0 = *(const float4*)&xs[basea];
        float4 M1 = *(const float4*)&xs[basea + 4];
        w10[ky][0] = xs[basea - 1];
        w10[ky][1] = M0.x; w10[ky][2] = M0.y; w10[ky][3] = M0.z; w10[ky][4] = M0.w;
        w10[ky][5] = M1.x; w10[ky][6] = M1.y; w10[ky][7] = M1.z; w10[ky][8] = M1.w;
        w10[ky][9] = xs[basea + 8];
      }
#pragma unroll
      for (int j = 0; j < 12; ++j) {
        float bias = brow[j];
        float a[8];
#pragma unroll
        for (int p = 0; p < 8; ++p) a[p] = bias;
#pragma unroll
        for (int ky = 0; ky < 3; ++ky)
#pragma unroll
          for (int kx = 0; kx < 3; ++kx) {
            float w = wrow[j * 9 + ky * 3 + kx];
#pragma unroll
            for (int p = 0; p < 8; ++p)
              a[p] = fmaf(w, w10[ky][kx + p], a[p]);
          }
        uint4 st;
        st.x = pack2(a[0], a[1]); st.y = pack2(a[2], a[3]);
        st.z = pack2(a[4], a[5]); st.w = pack2(a[6], a[7]);
        if (j < 4)      *(uint4*)(qg + basep[j] + p0) = st;
        else if (j < 8) *(uint4*)(kg + basep[j] + p0) = st;
        else            *(uint4*)(vg + basep[j] + p0) = st;
        if (j < 8) {
          float s2 = 0.f;
#pragma unroll
          for (int p = 0; p < 8; ++p) s2 = fmaf(a[p], a[p], s2);
          ssq[j] += s2;
        }
      }
    }
  }
#pragma unroll
  for (int j = 0; j < 8; ++j) {
    float v = ssq[j];
#pragma unroll
    for (int off = 32; off > 0; off >>= 1) v += __shfl_down(v, off);
    if (lane == 0) red[wave * 8 + j] = v;
  }
  __syncthreads();
  if (tid < 8) {
    float s = red[tid] + red[8 + tid] + red[16 + tid] + red[24 + tid];
    if (tid < 4) qn2[nidx[tid]] = s;
    else         kn2[nidx[tid]] = s;
  }
}

// ---------------------------------------------------------------- K2a: gram partials via MFMA, LDS-staged
// REVERTED to R7-verified BK=64 version (ran inside the 232.9us best total).
// Per BK=64 step: stage q[64][64] + k[64][64] into padded LDS, double-buffered,
// reg-staged (issue loads -> compute -> ds_write -> barrier).
__global__ __launch_bounds__(256) void k2_gram(
    const bf16* __restrict__ qg, const bf16* __restrict__ kg,
    float* __restrict__ part) {
  __shared__ unsigned short sq[2][64 * KPAD];   // 17408 B
  __shared__ unsigned short sk[2][64 * KPAD];   // 17408 B
  int tid = threadIdx.x;
  int wave = tid >> 6;           // 0..3 -> d-tile
  int lane = tid & 63;
  int chunk = blockIdx.x;        // 0..15
  int bh = blockIdx.y;           // 0..63
  const size_t base = (size_t)bh * HD * HW;
  int n0 = chunk * CHUNK;

  int srow = tid >> 3;           // 0..31
  int sseg = tid & 7;            // 0..7 (8px each)
  const bf16* qs0 = qg + base + (size_t)srow * HW + n0 + sseg * 8;
  const bf16* qs1 = qs0 + (size_t)32 * HW;
  const bf16* ks0 = kg + base + (size_t)srow * HW + n0 + sseg * 8;
  const bf16* ks1 = ks0 + (size_t)32 * HW;
  int d0 = srow * KPAD + sseg * 8;
  int d1 = (srow + 32) * KPAD + sseg * 8;

  int m = lane & 15;
  int k8 = lane >> 4;            // 0..3
  int arow = wave * 16 + m;

  f32x4 acc0 = {0.f, 0.f, 0.f, 0.f}, acc1 = acc0, acc2 = acc0, acc3 = acc0;

  uint4 rq0 = *(const uint4*)(qs0);
  uint4 rq1 = *(const uint4*)(qs1);
  uint4 rk0 = *(const uint4*)(ks0);
  uint4 rk1 = *(const uint4*)(ks1);
  ldsst(&sq[0][d0], rq0); ldsst(&sq[0][d1], rq1);
  ldsst(&sk[0][d0], rk0); ldsst(&sk[0][d1], rk1);
  __syncthreads();

#pragma unroll 1
  for (int s = 0; s < 9; ++s) {
    if (s < 8) {                       // issue next-step loads early (T14)
      int off = (s + 1) * 64;
      rq0 = *(const uint4*)(qs0 + off);
      rq1 = *(const uint4*)(qs1 + off);
      rk0 = *(const uint4*)(ks0 + off);
      rk1 = *(const uint4*)(ks1 + off);
    }
    const unsigned short* sqc = sq[s & 1];
    const unsigned short* skc = sk[s & 1];
#pragma unroll
    for (int kk = 0; kk < 2; ++kk) {
      int co = kk * 32 + k8 * 8;
      frag16 a  = ldsfrag(&sqc[arow * KPAD + co]);
      frag16 b0 = ldsfrag(&skc[(m +  0) * KPAD + co]);
      frag16 b1 = ldsfrag(&skc[(m + 16) * KPAD + co]);
      frag16 b2 = ldsfrag(&skc[(m + 32) * KPAD + co]);
      frag16 b3 = ldsfrag(&skc[(m + 48) * KPAD + co]);
      acc0 = __builtin_amdgcn_mfma_f32_16x16x32_bf16(a, b0, acc0, 0, 0, 0);
      acc1 = __builtin_amdgcn_mfma_f32_16x16x32_bf16(a, b1, acc1, 0, 0, 0);
      acc2 = __builtin_amdgcn_mfma_f32_16x16x32_bf16(a, b2, acc2, 0, 0, 0);
      acc3 = __builtin_amdgcn_mfma_f32_16x16x32_bf16(a, b3, acc3, 0, 0, 0);
    }
    if (s < 8) {
      int nb = (s + 1) & 1;
      ldsst(&sq[nb][d0], rq0); ldsst(&sq[nb][d1], rq1);
      ldsst(&sk[nb][d0], rk0); ldsst(&sk[nb][d1], rk1);
      __syncthreads();
    }
  }

  // C/D layout: row(d) = (lane>>4)*4 + r, col(e) = lane&15
  float* po = part + (size_t)(bh * NCH + chunk) * 4096;
  int dr = wave * 16 + (lane >> 4) * 4;
  int e0 = lane & 15;
#pragma unroll
  for (int r = 0; r < 4; ++r) {
    po[(dr + r) * 64 +  0 + e0] = acc0[r];
    po[(dr + r) * 64 + 16 + e0] = acc1[r];
    po[(dr + r) * 64 + 32 + e0] = acc2[r];
    po[(dr + r) * 64 + 48 + e0] = acc3[r];
  }
}

// ---------------------------------------------------------------- K2b: reduce partials + normalize + softmax
__global__ __launch_bounds__(256) void k2_softmax(
    const float* __restrict__ part, bf16* __restrict__ ah, bf16* __restrict__ al,
    const float* __restrict__ qn2, const float* __restrict__ kn2,
    const float* __restrict__ t_f) {
  __shared__ float kns[64];
  int bh = blockIdx.x;
  int dq = blockIdx.y;
  int tid = threadIdx.x;
  if (tid < 64) kns[tid] = fmaxf(sqrtf(kn2[bh * 64 + tid]), 1e-12f);
  __syncthreads();
  int d  = dq * 16 + (tid >> 4);
  int e0 = (tid & 15) * 4;

  const float* pb = part + (size_t)bh * NCH * 4096 + d * 64 + e0;
  float4 s = make_float4(0.f, 0.f, 0.f, 0.f);
#pragma unroll
  for (int ch = 0; ch < NCH; ++ch) {
    float4 g = *(const float4*)&pb[ch * 4096];
    s.x += g.x; s.y += g.y; s.z += g.z; s.w += g.w;
  }
  float v[4] = {s.x, s.y, s.z, s.w};
  float sc = t_f[bh & 7] / fmaxf(sqrtf(qn2[bh * 64 + d]), 1e-12f);
  float m = -1e30f;
#pragma unroll
  for (int j = 0; j < 4; ++j) {
    v[j] = v[j] * sc / kns[e0 + j];
    m = fmaxf(m, v[j]);
  }
  m = fmaxf(m, __shfl_xor(m, 1));
  m = fmaxf(m, __shfl_xor(m, 2));
  m = fmaxf(m, __shfl_xor(m, 4));
  m = fmaxf(m, __shfl_xor(m, 8));
  float ssum = 0.f;
#pragma unroll
  for (int j = 0; j < 4; ++j) { v[j] = __expf(v[j] - m); ssum += v[j]; }
  ssum += __shfl_xor(ssum, 1);
  ssum += __shfl_xor(ssum, 2);
  ssum += __shfl_xor(ssum, 4);
  ssum += __shfl_xor(ssum, 8);
  float inv = 1.f / ssum;
  unsigned short hi16[4], lo16[4];
#pragma unroll
  for (int j = 0; j < 4; ++j) {
    float p = v[j] * inv;
    bf16 hi = f2b(p);
    float lo = p - b2f(hi);
    bf16 lov = f2b(lo);
    hi16[j] = *(unsigned short*)&hi;
    lo16[j] = *(unsigned short*)&lov;
  }
  const size_t base = (size_t)bh * 4096 + d * 64 + e0;
  *(ushort4*)(ah + base) = *(ushort4*)&hi16[0];
  *(ushort4*)(al + base) = *(ushort4*)&lo16[0];
}

// ---------------------------------------------------------------- K3: o = attn @ v via MFMA
// v2 (unchanged from R12 submission — being measured this round): v-tile transposed
// into LDS via register 4x4 transposes; B-frags = single 16B LDS reads.
__global__ __launch_bounds__(256) void k3_av(
    const bf16* __restrict__ ah, const bf16* __restrict__ al,
    const bf16* __restrict__ vg, bf16* __restrict__ og) {
  __shared__ unsigned short vt[256 * VTPAD];   // 34816 B: v^T tile [n_local][e]
  int tid = threadIdx.x;
  int wave = tid >> 6, lane = tid & 63;
  int chunk = blockIdx.x;   // 0..35 (256 pixels each)
  int bh = blockIdx.y;      // 0..63
  int b = bh >> 3, h = bh & 7;
  int n0 = chunk * 256;
  int m = lane & 15;
  int k8 = (lane >> 4) * 8;
  int nwbase = wave * 64;

  const bf16* vp0 = vg + (size_t)bh * HD * HW + n0;
#pragma unroll
  for (int it = 0; it < 4; ++it) {
    int u = it * 256 + tid;
    int eq = u & 15, nq = u >> 4;     // e = eq*4, n_local = nq*4
    const bf16* src = vp0 + (size_t)(eq * 4) * HW + nq * 4;
    ushort4 r0 = *(const ushort4*)(src);
    ushort4 r1 = *(const ushort4*)(src + HW);
    ushort4 r2 = *(const ushort4*)(src + 2 * HW);
    ushort4 r3 = *(const ushort4*)(src + (size_t)3 * HW);
    unsigned short* dst = &vt[(nq * 4) * VTPAD + eq * 4];
    *(ushort4*)(dst)             = make_ushort4(r0.x, r1.x, r2.x, r3.x);
    *(ushort4*)(dst + VTPAD)     = make_ushort4(r0.y, r1.y, r2.y, r3.y);
    *(ushort4*)(dst + 2 * VTPAD) = make_ushort4(r0.z, r1.z, r2.z, r3.z);
    *(ushort4*)(dst + 3 * VTPAD) = make_ushort4(r0.w, r1.w, r2.w, r3.w);
  }
  __syncthreads();

  const bf16* ahp = ah + (size_t)bh * 4096;
  const bf16* alp = al + (size_t)bh * 4096;

  f32x4 acc[4][4];
#pragma unroll
  for (int dt = 0; dt < 4; ++dt)
#pragma unroll
    for (int nt = 0; nt < 4; ++nt) acc[dt][nt] = {0.f, 0.f, 0.f, 0.f};

#pragma unroll
  for (int dt = 0; dt < 4; ++dt) {
    frag16 ahf[2], alf[2];
#pragma unroll
    for (int kh = 0; kh < 2; ++kh) {
      ahf[kh] = *(const frag16*)(ahp + (dt * 16 + m) * 64 + kh * 32 + k8);
      alf[kh] = *(const frag16*)(alp + (dt * 16 + m) * 64 + kh * 32 + k8);
    }
#pragma unroll
    for (int nt = 0; nt < 4; ++nt) {
      int nl = nwbase + nt * 16 + m;
#pragma unroll
      for (int kh = 0; kh < 2; ++kh) {
        frag16 bf = ldsfrag(&vt[nl * VTPAD + kh * 32 + k8]);
        acc[dt][nt] = __builtin_amdgcn_mfma_f32_16x16x32_bf16(ahf[kh], bf, acc[dt][nt], 0, 0, 0);
        acc[dt][nt] = __builtin_amdgcn_mfma_f32_16x16x32_bf16(alf[kh], bf, acc[dt][nt], 0, 0, 0);
      }
    }
  }

  int cc0 = (h & 1) * 256 + (h >> 1);
  bf16* ob = og + (size_t)b * 512 * HW;
  int q4 = (lane >> 4) * 4;
#pragma unroll
  for (int dt = 0; dt < 4; ++dt)
#pragma unroll
    for (int nt = 0; nt < 4; ++nt) {
      int n = n0 + nwbase + nt * 16 + m;
#pragma unroll
      for (int r = 0; r < 4; ++r) {
        int d = dt * 16 + q4 + r;
        ob[(size_t)(cc0 + d * 4) * HW + n] = f2b(acc[dt][nt][r]);
      }
    }
}

// ---------------------------------------------------------------- K4: fused grouped 3x3 conv (4 in-ch -> 1 out-ch)
// bf16 channel-interleaved cells (verified ~22us): 20.8 KB, 7 blocks/CU.
__global__ __launch_bounds__(256) void k4_fuse(
    const bf16* __restrict__ og, const float* __restrict__ wf,
    const float* __restrict__ bfu, float* __restrict__ out) {
  __shared__ unsigned short cells[26 * 100 * 4];   // 20800 B
  int tid = threadIdx.x;
  int tile = blockIdx.x;                // 0..3
  int bc = blockIdx.y;                  // 0..1023
  int b = bc >> 7, c = bc & 127;
  int r0 = tile * 24 - 1;
  const uint2 z2 = make_uint2(0u, 0u);
  for (int i = tid; i < 52; i += 256) {
    int rr = i >> 1, cc = (i & 1) ? 98 : 1;
    *(uint2*)&cells[(rr * 100 + cc) * 4] = z2;
  }
  const uint4 z4 = make_uint4(0u, 0u, 0u, 0u);
  if (r0 < 0)
    for (int i = tid; i < 48; i += 256) *(uint4*)&cells[(0 * 100 + 2 + i * 2) * 4] = z4;
  if (r0 + 25 >= 96)
    for (int i = tid; i < 48; i += 256) *(uint4*)&cells[(25 * 100 + 2 + i * 2) * 4] = z4;
  const bf16* op = og + (size_t)(b * 512 + c * 4) * HW;
  for (int u = tid; u < 26 * 48; u += 256) {
    int rr = u / 48, pr = u - rr * 48;
    int gr = r0 + rr;
    if (gr >= 0 && gr < 96) {
      int gp = gr * 96 + pr * 2;
      unsigned int A = *(const unsigned int*)(op + gp);
      unsigned int B = *(const unsigned int*)(op + HW + gp);
      unsigned int C = *(const unsigned int*)(op + 2 * HW + gp);
      unsigned int D = *(const unsigned int*)(op + (size_t)3 * HW + gp);
      uint4 w;
      w.x = (A & 0xffffu) | (B << 16);          // px0: ch0|ch1
      w.y = (C & 0xffffu) | (D << 16);          // px0: ch2|ch3
      w.z = (A >> 16) | (B & 0xffff0000u);      // px1: ch0|ch1
      w.w = (C >> 16) | (D & 0xffff0000u);      // px1: ch2|ch3
      *(uint4*)&cells[(rr * 100 + 2 + pr * 2) * 4] = w;
    }
  }
  __syncthreads();
  const float* wrow = wf + c * 36;      // uniform -> s_load
  float bias = bfu[c];
  float* outp = out + (size_t)(b * CC + c) * HW + tile * 24 * 96;
#pragma unroll
  for (int pi = 0; pi < 9; ++pi) {
    int p = pi * 256 + tid;
    int ry = p / 96, x = p - ry * 96;
    float a0 = bias, a1 = 0.f, a2 = 0.f, a3 = 0.f;
#pragma unroll
    for (int ky = 0; ky < 3; ++ky) {
      int basec = (ry + ky) * 100 + 1 + x;
#pragma unroll
      for (int kx = 0; kx < 3; ++kx) {
        uint2 cc2 = *(const uint2*)&cells[(basec + kx) * 4];   // b64, 2 lanes/bank
        a0 = fmaf(wrow[0 + ky * 3 + kx],  lo2f(cc2.x), a0);
        a1 = fmaf(wrow[9 + ky * 3 + kx],  hi2f(cc2.x), a1);
        a2 = fmaf(wrow[18 + ky * 3 + kx], lo2f(cc2.y), a2);
        a3 = fmaf(wrow[27 + ky * 3 + kx], hi2f(cc2.y), a3);
      }
    }
    outp[p] = (a0 + a1) + (a2 + a3);
  }
}

// ---------------------------------------------------------------- launcher
extern "C" void kernel_launch(void* const* d_in, const int* in_sizes, int n_in,
                              void* d_out, int out_size, void* d_ws, size_t ws_size,
                              hipStream_t stream) {
  (void)in_sizes; (void)n_in; (void)out_size; (void)ws_size;
  const float* x   = (const float*)d_in[0];
  const float* wq  = (const float*)d_in[1];
  const float* bq  = (const float*)d_in[2];
  const float* tt  = (const float*)d_in[3];
  const float* wf  = (const float*)d_in[4];
  const float* bfu = (const float*)d_in[5];

  // workspace layout (~245 MB)
  char* ws = (char*)d_ws;
  bf16*  qg    = (bf16*)(ws + 0);                 // 75497472 B, later aliased by og
  bf16*  kg    = (bf16*)(ws + 75497472);          // 75497472 B
  bf16*  vg    = (bf16*)(ws + 150994944);         // 75497472 B
  float* part  = (float*)(ws + 226492416);        // 16777216 B
  bf16*  ah    = (bf16*)(ws + 243269632);         // 524288 B
  bf16*  al    = (bf16*)(ws + 243793920);         // 524288 B
  float* qn2   = (float*)(ws + 244318208);        // 16384 B
  float* kn2   = (float*)(ws + 244334592);        // 16384 B
  bf16*  og    = qg;                              // q is dead after k2_gram
  float* out   = (float*)d_out;

  // k1 split into two half-batch dispatches (observability round)
  hipLaunchKernelGGL(k1_qkv, dim3(512), dim3(256), 0, stream,
                     x, wq, bq, qg, kg, vg, qn2, kn2, 0);
  hipLaunchKernelGGL(k1_qkv, dim3(512), dim3(256), 0, stream,
                     x, wq, bq, qg, kg, vg, qn2, kn2, 4);
  hipLaunchKernelGGL(k2_gram, dim3(NCH, 64), dim3(256), 0, stream, qg, kg, part);
  hipLaunchKernelGGL(k2_softmax, dim3(64, 4), dim3(256), 0, stream,
                     part, ah, al, qn2, kn2, tt);
  hipLaunchKernelGGL(k3_av, dim3(36, 64), dim3(256), 0, stream, ah, al, vg, og);
  hipLaunchKernelGGL(k4_fuse, dim3(4, 1024), dim3(256), 0, stream, og, wf, bfu, out);
}

// Round 15
// 250.433 us; speedup vs baseline: 1.0054x; 1.0054x over previous
//
#include <hip/hip_runtime.h>
#include <hip/hip_bf16.h>
#include <stdint.h>

// Problem constants
#define BB     8
#define CC     128
#define HW     9216      // 96*96
#define NHEAD  8
#define HD     64
#define NCH    16        // gram n-chunks
#define CHUNK  576       // HW/NCH
#define KPAD   68        // gram LDS row (ushort): 64 px + 4 pad = 136B stride
#define VTPAD  68        // k3 v^T LDS row (ushort): 64 e + 4 pad = 136B stride

typedef __hip_bfloat16 bf16;
using frag16 = __attribute__((ext_vector_type(8))) short;  // 8 bf16 (4 VGPRs)
using f32x4  = __attribute__((ext_vector_type(4))) float;

__device__ __forceinline__ float b2f(bf16 v) { return __bfloat162float(v); }
__device__ __forceinline__ bf16  f2b(float v) { return __float2bfloat16(v); }

__device__ __forceinline__ float lo2f(unsigned int u) {
  union { unsigned int i; float f; } c; c.i = u << 16; return c.f;
}
__device__ __forceinline__ float hi2f(unsigned int u) {
  union { unsigned int i; float f; } c; c.i = u & 0xffff0000u; return c.f;
}

__device__ __forceinline__ unsigned int pack2(float a, float b) {
  union { __hip_bfloat162 h2; unsigned int u; } c;
  c.h2 = __float22bfloat162_rn(make_float2(a, b));   // v_cvt_pk_bf16_f32
  return c.u;
}

// LDS frag read from 8B-aligned address
__device__ __forceinline__ frag16 ldsfrag(const unsigned short* p) {
  uint2 lo = *(const uint2*)p;
  uint2 hi = *(const uint2*)(p + 4);
  union { unsigned int u[4]; frag16 f; } c;
  c.u[0] = lo.x; c.u[1] = lo.y; c.u[2] = hi.x; c.u[3] = hi.y;
  return c.f;
}
// LDS 16B store as two 8B stores (8B-aligned dst)
__device__ __forceinline__ void ldsst(unsigned short* p, uint4 v) {
  *(uint2*)p = make_uint2(v.x, v.y);
  *(uint2*)(p + 4) = make_uint2(v.z, v.w);
}

// Shared staging for k1: zero-pad halo only (interior fully overwritten), then stage plane.
__device__ __forceinline__ void stage_plane(float* xs, const float* xp, int tid) {
  const float4 z4 = make_float4(0.f, 0.f, 0.f, 0.f);
  for (int i = tid; i < 98; i += 256) *(float4*)&xs[i * 100] = z4;        // cols 0..3
  for (int i = tid; i < 24; i += 256) *(float4*)&xs[4 + i * 4] = z4;     // row 0
  for (int i = tid; i < 25; i += 256) *(float4*)&xs[9704 + i * 4] = z4;  // row 97 + guard
  for (int i = tid; i < 96 * 24; i += 256) {
    int y = i / 24, g4 = i - y * 24;
    ((float4*)(xs + (y + 1) * 100 + 4))[g4] = ((const float4*)(xp + y * 96))[g4];
  }
}

// ---------------------------------------------------------------- K1: qkv depthwise conv + q/k norms
// block = (b, c), full 96x96 plane in LDS. Split 2x512 (b_base) kept one more round
// for observability of k3v3 (~12us rent).
__global__ __launch_bounds__(256) void k1_qkv(
    const float* __restrict__ x, const float* __restrict__ wq,
    const float* __restrict__ bq,
    bf16* __restrict__ qg, bf16* __restrict__ kg, bf16* __restrict__ vg,
    float* __restrict__ qn2, float* __restrict__ kn2, int b_base) {
  __shared__ float xs[98 * 100 + 4];
  __shared__ float red[32];
  int tid = threadIdx.x;
  int wave = tid >> 6, lane = tid & 63;
  int b = b_base + (blockIdx.x >> 7), c = blockIdx.x & 127;
  const float* xp = x + (size_t)(b * CC + c) * HW;
  stage_plane(xs, xp, tid);
  __syncthreads();

  int half = c >> 6, d = c & 63;
  int nidx[8];
  size_t basep[12];
#pragma unroll
  for (int j = 0; j < 12; ++j) {
    int e = j & 3;
    int h = e * 2 + half;
    int ni = (b * NHEAD + h) * HD + d;
    if (j < 8) nidx[j] = ni;
    basep[j] = (size_t)ni * HW;
  }
  const float* wrow = wq + c * 108;
  const float* brow = bq + c * 12;

  float ssq[8];
#pragma unroll
  for (int j = 0; j < 8; ++j) ssq[j] = 0.f;

#pragma unroll 1
  for (int it = 0; it < 5; ++it) {
    int u = it * 256 + tid;
    if (u < 1152) {
      int ly = u / 12;
      int x8 = (u - ly * 12) * 8;
      int p0 = ly * 96 + x8;
      float w10[3][10];
#pragma unroll
      for (int ky = 0; ky < 3; ++ky) {
        int basea = (ly + ky) * 100 + 4 + x8;
        float4 M0 = *(const float4*)&xs[basea];
        float4 M1 = *(const float4*)&xs[basea + 4];
        w10[ky][0] = xs[basea - 1];
        w10[ky][1] = M0.x; w10[ky][2] = M0.y; w10[ky][3] = M0.z; w10[ky][4] = M0.w;
        w10[ky][5] = M1.x; w10[ky][6] = M1.y; w10[ky][7] = M1.z; w10[ky][8] = M1.w;
        w10[ky][9] = xs[basea + 8];
      }
#pragma unroll
      for (int j = 0; j < 12; ++j) {
        float bias = brow[j];
        float a[8];
#pragma unroll
        for (int p = 0; p < 8; ++p) a[p] = bias;
#pragma unroll
        for (int ky = 0; ky < 3; ++ky)
#pragma unroll
          for (int kx = 0; kx < 3; ++kx) {
            float w = wrow[j * 9 + ky * 3 + kx];
#pragma unroll
            for (int p = 0; p < 8; ++p)
              a[p] = fmaf(w, w10[ky][kx + p], a[p]);
          }
        uint4 st;
        st.x = pack2(a[0], a[1]); st.y = pack2(a[2], a[3]);
        st.z = pack2(a[4], a[5]); st.w = pack2(a[6], a[7]);
        if (j < 4)      *(uint4*)(qg + basep[j] + p0) = st;
        else if (j < 8) *(uint4*)(kg + basep[j] + p0) = st;
        else            *(uint4*)(vg + basep[j] + p0) = st;
        if (j < 8) {
          float s2 = 0.f;
#pragma unroll
          for (int p = 0; p < 8; ++p) s2 = fmaf(a[p], a[p], s2);
          ssq[j] += s2;
        }
      }
    }
  }
#pragma unroll
  for (int j = 0; j < 8; ++j) {
    float v = ssq[j];
#pragma unroll
    for (int off = 32; off > 0; off >>= 1) v += __shfl_down(v, off);
    if (lane == 0) red[wave * 8 + j] = v;
  }
  __syncthreads();
  if (tid < 8) {
    float s = red[tid] + red[8 + tid] + red[16 + tid] + red[24 + tid];
    if (tid < 4) qn2[nidx[tid]] = s;
    else         kn2[nidx[tid]] = s;
  }
}

// ---------------------------------------------------------------- K2a: gram partials via MFMA, LDS-staged
// R7-verified BK=64 version (ran inside the 232.9us best total).
__global__ __launch_bounds__(256) void k2_gram(
    const bf16* __restrict__ qg, const bf16* __restrict__ kg,
    float* __restrict__ part) {
  __shared__ unsigned short sq[2][64 * KPAD];   // 17408 B
  __shared__ unsigned short sk[2][64 * KPAD];   // 17408 B
  int tid = threadIdx.x;
  int wave = tid >> 6;           // 0..3 -> d-tile
  int lane = tid & 63;
  int chunk = blockIdx.x;        // 0..15
  int bh = blockIdx.y;           // 0..63
  const size_t base = (size_t)bh * HD * HW;
  int n0 = chunk * CHUNK;

  int srow = tid >> 3;           // 0..31
  int sseg = tid & 7;            // 0..7 (8px each)
  const bf16* qs0 = qg + base + (size_t)srow * HW + n0 + sseg * 8;
  const bf16* qs1 = qs0 + (size_t)32 * HW;
  const bf16* ks0 = kg + base + (size_t)srow * HW + n0 + sseg * 8;
  const bf16* ks1 = ks0 + (size_t)32 * HW;
  int d0 = srow * KPAD + sseg * 8;
  int d1 = (srow + 32) * KPAD + sseg * 8;

  int m = lane & 15;
  int k8 = lane >> 4;            // 0..3
  int arow = wave * 16 + m;

  f32x4 acc0 = {0.f, 0.f, 0.f, 0.f}, acc1 = acc0, acc2 = acc0, acc3 = acc0;

  uint4 rq0 = *(const uint4*)(qs0);
  uint4 rq1 = *(const uint4*)(qs1);
  uint4 rk0 = *(const uint4*)(ks0);
  uint4 rk1 = *(const uint4*)(ks1);
  ldsst(&sq[0][d0], rq0); ldsst(&sq[0][d1], rq1);
  ldsst(&sk[0][d0], rk0); ldsst(&sk[0][d1], rk1);
  __syncthreads();

#pragma unroll 1
  for (int s = 0; s < 9; ++s) {
    if (s < 8) {                       // issue next-step loads early (T14)
      int off = (s + 1) * 64;
      rq0 = *(const uint4*)(qs0 + off);
      rq1 = *(const uint4*)(qs1 + off);
      rk0 = *(const uint4*)(ks0 + off);
      rk1 = *(const uint4*)(ks1 + off);
    }
    const unsigned short* sqc = sq[s & 1];
    const unsigned short* skc = sk[s & 1];
#pragma unroll
    for (int kk = 0; kk < 2; ++kk) {
      int co = kk * 32 + k8 * 8;
      frag16 a  = ldsfrag(&sqc[arow * KPAD + co]);
      frag16 b0 = ldsfrag(&skc[(m +  0) * KPAD + co]);
      frag16 b1 = ldsfrag(&skc[(m + 16) * KPAD + co]);
      frag16 b2 = ldsfrag(&skc[(m + 32) * KPAD + co]);
      frag16 b3 = ldsfrag(&skc[(m + 48) * KPAD + co]);
      acc0 = __builtin_amdgcn_mfma_f32_16x16x32_bf16(a, b0, acc0, 0, 0, 0);
      acc1 = __builtin_amdgcn_mfma_f32_16x16x32_bf16(a, b1, acc1, 0, 0, 0);
      acc2 = __builtin_amdgcn_mfma_f32_16x16x32_bf16(a, b2, acc2, 0, 0, 0);
      acc3 = __builtin_amdgcn_mfma_f32_16x16x32_bf16(a, b3, acc3, 0, 0, 0);
    }
    if (s < 8) {
      int nb = (s + 1) & 1;
      ldsst(&sq[nb][d0], rq0); ldsst(&sq[nb][d1], rq1);
      ldsst(&sk[nb][d0], rk0); ldsst(&sk[nb][d1], rk1);
      __syncthreads();
    }
  }

  // C/D layout: row(d) = (lane>>4)*4 + r, col(e) = lane&15
  float* po = part + (size_t)(bh * NCH + chunk) * 4096;
  int dr = wave * 16 + (lane >> 4) * 4;
  int e0 = lane & 15;
#pragma unroll
  for (int r = 0; r < 4; ++r) {
    po[(dr + r) * 64 +  0 + e0] = acc0[r];
    po[(dr + r) * 64 + 16 + e0] = acc1[r];
    po[(dr + r) * 64 + 32 + e0] = acc2[r];
    po[(dr + r) * 64 + 48 + e0] = acc3[r];
  }
}

// ---------------------------------------------------------------- K2b: reduce partials + normalize + softmax
__global__ __launch_bounds__(256) void k2_softmax(
    const float* __restrict__ part, bf16* __restrict__ ah, bf16* __restrict__ al,
    const float* __restrict__ qn2, const float* __restrict__ kn2,
    const float* __restrict__ t_f) {
  __shared__ float kns[64];
  int bh = blockIdx.x;
  int dq = blockIdx.y;
  int tid = threadIdx.x;
  if (tid < 64) kns[tid] = fmaxf(sqrtf(kn2[bh * 64 + tid]), 1e-12f);
  __syncthreads();
  int d  = dq * 16 + (tid >> 4);
  int e0 = (tid & 15) * 4;

  const float* pb = part + (size_t)bh * NCH * 4096 + d * 64 + e0;
  float4 s = make_float4(0.f, 0.f, 0.f, 0.f);
#pragma unroll
  for (int ch = 0; ch < NCH; ++ch) {
    float4 g = *(const float4*)&pb[ch * 4096];
    s.x += g.x; s.y += g.y; s.z += g.z; s.w += g.w;
  }
  float v[4] = {s.x, s.y, s.z, s.w};
  float sc = t_f[bh & 7] / fmaxf(sqrtf(qn2[bh * 64 + d]), 1e-12f);
  float m = -1e30f;
#pragma unroll
  for (int j = 0; j < 4; ++j) {
    v[j] = v[j] * sc / kns[e0 + j];
    m = fmaxf(m, v[j]);
  }
  m = fmaxf(m, __shfl_xor(m, 1));
  m = fmaxf(m, __shfl_xor(m, 2));
  m = fmaxf(m, __shfl_xor(m, 4));
  m = fmaxf(m, __shfl_xor(m, 8));
  float ssum = 0.f;
#pragma unroll
  for (int j = 0; j < 4; ++j) { v[j] = __expf(v[j] - m); ssum += v[j]; }
  ssum += __shfl_xor(ssum, 1);
  ssum += __shfl_xor(ssum, 2);
  ssum += __shfl_xor(ssum, 4);
  ssum += __shfl_xor(ssum, 8);
  float inv = 1.f / ssum;
  unsigned short hi16[4], lo16[4];
#pragma unroll
  for (int j = 0; j < 4; ++j) {
    float p = v[j] * inv;
    bf16 hi = f2b(p);
    float lo = p - b2f(hi);
    bf16 lov = f2b(lo);
    hi16[j] = *(unsigned short*)&hi;
    lo16[j] = *(unsigned short*)&lov;
  }
  const size_t base = (size_t)bh * 4096 + d * 64 + e0;
  *(ushort4*)(ah + base) = *(ushort4*)&hi16[0];
  *(ushort4*)(al + base) = *(ushort4*)&lo16[0];
}

// ---------------------------------------------------------------- K3: o = attn @ v via MFMA
// v3 = old 41us structure (A-frags hoisted FIRST -> latency hides under staging+barrier;
// nt-outer loop; scalar epilogue) with ONLY the v-gather replaced by the verified LDS
// transpose. B-frags per-nt from LDS (4 ds_read_b64, ~120cyc, pipelined) keeps VGPR in
// the old 3-waves/SIMD class. Single variable vs the 41us parent.
__global__ __launch_bounds__(256) void k3_av(
    const bf16* __restrict__ ah, const bf16* __restrict__ al,
    const bf16* __restrict__ vg, bf16* __restrict__ og) {
  __shared__ unsigned short vt[256 * VTPAD];   // 34816 B: v^T tile [n_local][e]
  int tid = threadIdx.x;
  int wave = tid >> 6, lane = tid & 63;
  int chunk = blockIdx.x;   // 0..35 (256 pixels each)
  int bh = blockIdx.y;      // 0..63
  int b = bh >> 3, h = bh & 7;
  int n0 = chunk * 256;
  int m = lane & 15;
  int k8 = (lane >> 4) * 8;
  int nwbase = wave * 64;

  // A-frags issued FIRST (old structure): global latency overlaps staging + barrier
  const bf16* ahp = ah + (size_t)bh * 4096;
  const bf16* alp = al + (size_t)bh * 4096;
  frag16 a_hi[4][2], a_lo[4][2];
#pragma unroll
  for (int dt = 0; dt < 4; ++dt)
#pragma unroll
    for (int kh = 0; kh < 2; ++kh) {
      a_hi[dt][kh] = *(const frag16*)(ahp + (dt * 16 + m) * 64 + kh * 32 + k8);
      a_lo[dt][kh] = *(const frag16*)(alp + (dt * 16 + m) * 64 + kh * 32 + k8);
    }

  // stage v^T (R12/13-verified): 4x(8B coalesced load) -> reg transpose -> 4x(8B write)
  const bf16* vp0 = vg + (size_t)bh * HD * HW + n0;
#pragma unroll
  for (int it = 0; it < 4; ++it) {
    int u = it * 256 + tid;
    int eq = u & 15, nq = u >> 4;     // e = eq*4, n_local = nq*4
    const bf16* src = vp0 + (size_t)(eq * 4) * HW + nq * 4;
    ushort4 r0 = *(const ushort4*)(src);
    ushort4 r1 = *(const ushort4*)(src + HW);
    ushort4 r2 = *(const ushort4*)(src + 2 * HW);
    ushort4 r3 = *(const ushort4*)(src + (size_t)3 * HW);
    unsigned short* dst = &vt[(nq * 4) * VTPAD + eq * 4];
    *(ushort4*)(dst)             = make_ushort4(r0.x, r1.x, r2.x, r3.x);
    *(ushort4*)(dst + VTPAD)     = make_ushort4(r0.y, r1.y, r2.y, r3.y);
    *(ushort4*)(dst + 2 * VTPAD) = make_ushort4(r0.z, r1.z, r2.z, r3.z);
    *(ushort4*)(dst + 3 * VTPAD) = make_ushort4(r0.w, r1.w, r2.w, r3.w);
  }
  __syncthreads();

  f32x4 acc[4][4];
#pragma unroll
  for (int dt = 0; dt < 4; ++dt)
#pragma unroll
    for (int nt = 0; nt < 4; ++nt) acc[dt][nt] = {0.f, 0.f, 0.f, 0.f};

  // nt-outer (old loop order): 2 B-frags per nt from LDS, reused across all dt
#pragma unroll
  for (int nt = 0; nt < 4; ++nt) {
    int nl = nwbase + nt * 16 + m;
    frag16 bf0 = ldsfrag(&vt[nl * VTPAD + 0 * 32 + k8]);
    frag16 bf1 = ldsfrag(&vt[nl * VTPAD + 1 * 32 + k8]);
#pragma unroll
    for (int dt = 0; dt < 4; ++dt) {
      acc[dt][nt] = __builtin_amdgcn_mfma_f32_16x16x32_bf16(a_hi[dt][0], bf0, acc[dt][nt], 0, 0, 0);
      acc[dt][nt] = __builtin_amdgcn_mfma_f32_16x16x32_bf16(a_lo[dt][0], bf0, acc[dt][nt], 0, 0, 0);
      acc[dt][nt] = __builtin_amdgcn_mfma_f32_16x16x32_bf16(a_hi[dt][1], bf1, acc[dt][nt], 0, 0, 0);
      acc[dt][nt] = __builtin_amdgcn_mfma_f32_16x16x32_bf16(a_lo[dt][1], bf1, acc[dt][nt], 0, 0, 0);
    }
  }

  int cc0 = (h & 1) * 256 + (h >> 1);
  bf16* ob = og + (size_t)b * 512 * HW;
  int q4 = (lane >> 4) * 4;
#pragma unroll
  for (int dt = 0; dt < 4; ++dt)
#pragma unroll
    for (int nt = 0; nt < 4; ++nt) {
      int n = n0 + nwbase + nt * 16 + m;
#pragma unroll
      for (int r = 0; r < 4; ++r) {
        int d = dt * 16 + q4 + r;
        ob[(size_t)(cc0 + d * 4) * HW + n] = f2b(acc[dt][nt][r]);
      }
    }
}

// ---------------------------------------------------------------- K4: fused grouped 3x3 conv (4 in-ch -> 1 out-ch)
// bf16 channel-interleaved cells (verified ~22us): 20.8 KB, 7 blocks/CU.
__global__ __launch_bounds__(256) void k4_fuse(
    const bf16* __restrict__ og, const float* __restrict__ wf,
    const float* __restrict__ bfu, float* __restrict__ out) {
  __shared__ unsigned short cells[26 * 100 * 4];   // 20800 B
  int tid = threadIdx.x;
  int tile = blockIdx.x;                // 0..3
  int bc = blockIdx.y;                  // 0..1023
  int b = bc >> 7, c = bc & 127;
  int r0 = tile * 24 - 1;
  const uint2 z2 = make_uint2(0u, 0u);
  for (int i = tid; i < 52; i += 256) {
    int rr = i >> 1, cc = (i & 1) ? 98 : 1;
    *(uint2*)&cells[(rr * 100 + cc) * 4] = z2;
  }
  const uint4 z4 = make_uint4(0u, 0u, 0u, 0u);
  if (r0 < 0)
    for (int i = tid; i < 48; i += 256) *(uint4*)&cells[(0 * 100 + 2 + i * 2) * 4] = z4;
  if (r0 + 25 >= 96)
    for (int i = tid; i < 48; i += 256) *(uint4*)&cells[(25 * 100 + 2 + i * 2) * 4] = z4;
  const bf16* op = og + (size_t)(b * 512 + c * 4) * HW;
  for (int u = tid; u < 26 * 48; u += 256) {
    int rr = u / 48, pr = u - rr * 48;
    int gr = r0 + rr;
    if (gr >= 0 && gr < 96) {
      int gp = gr * 96 + pr * 2;
      unsigned int A = *(const unsigned int*)(op + gp);
      unsigned int B = *(const unsigned int*)(op + HW + gp);
      unsigned int C = *(const unsigned int*)(op + 2 * HW + gp);
      unsigned int D = *(const unsigned int*)(op + (size_t)3 * HW + gp);
      uint4 w;
      w.x = (A & 0xffffu) | (B << 16);          // px0: ch0|ch1
      w.y = (C & 0xffffu) | (D << 16);          // px0: ch2|ch3
      w.z = (A >> 16) | (B & 0xffff0000u);      // px1: ch0|ch1
      w.w = (C >> 16) | (D & 0xffff0000u);      // px1: ch2|ch3
      *(uint4*)&cells[(rr * 100 + 2 + pr * 2) * 4] = w;
    }
  }
  __syncthreads();
  const float* wrow = wf + c * 36;      // uniform -> s_load
  float bias = bfu[c];
  float* outp = out + (size_t)(b * CC + c) * HW + tile * 24 * 96;
#pragma unroll
  for (int pi = 0; pi < 9; ++pi) {
    int p = pi * 256 + tid;
    int ry = p / 96, x = p - ry * 96;
    float a0 = bias, a1 = 0.f, a2 = 0.f, a3 = 0.f;
#pragma unroll
    for (int ky = 0; ky < 3; ++ky) {
      int basec = (ry + ky) * 100 + 1 + x;
#pragma unroll
      for (int kx = 0; kx < 3; ++kx) {
        uint2 cc2 = *(const uint2*)&cells[(basec + kx) * 4];   // b64, 2 lanes/bank
        a0 = fmaf(wrow[0 + ky * 3 + kx],  lo2f(cc2.x), a0);
        a1 = fmaf(wrow[9 + ky * 3 + kx],  hi2f(cc2.x), a1);
        a2 = fmaf(wrow[18 + ky * 3 + kx], lo2f(cc2.y), a2);
        a3 = fmaf(wrow[27 + ky * 3 + kx], hi2f(cc2.y), a3);
      }
    }
    outp[p] = (a0 + a1) + (a2 + a3);
  }
}

// ---------------------------------------------------------------- launcher
extern "C" void kernel_launch(void* const* d_in, const int* in_sizes, int n_in,
                              void* d_out, int out_size, void* d_ws, size_t ws_size,
                              hipStream_t stream) {
  (void)in_sizes; (void)n_in; (void)out_size; (void)ws_size;
  const float* x   = (const float*)d_in[0];
  const float* wq  = (const float*)d_in[1];
  const float* bq  = (const float*)d_in[2];
  const float* tt  = (const float*)d_in[3];
  const float* wf  = (const float*)d_in[4];
  const float* bfu = (const float*)d_in[5];

  // workspace layout (~245 MB)
  char* ws = (char*)d_ws;
  bf16*  qg    = (bf16*)(ws + 0);                 // 75497472 B, later aliased by og
  bf16*  kg    = (bf16*)(ws + 75497472);          // 75497472 B
  bf16*  vg    = (bf16*)(ws + 150994944);         // 75497472 B
  float* part  = (float*)(ws + 226492416);        // 16777216 B
  bf16*  ah    = (bf16*)(ws + 243269632);         // 524288 B
  bf16*  al    = (bf16*)(ws + 243793920);         // 524288 B
  float* qn2   = (float*)(ws + 244318208);        // 16384 B
  float* kn2   = (float*)(ws + 244334592);        // 16384 B
  bf16*  og    = qg;                              // q is dead after k2_gram
  float* out   = (float*)d_out;

  // k1 split into two half-batch dispatches (observability round)
  hipLaunchKernelGGL(k1_qkv, dim3(512), dim3(256), 0, stream,
                     x, wq, bq, qg, kg, vg, qn2, kn2, 0);
  hipLaunchKernelGGL(k1_qkv, dim3(512), dim3(256), 0, stream,
                     x, wq, bq, qg, kg, vg, qn2, kn2, 4);
  hipLaunchKernelGGL(k2_gram, dim3(NCH, 64), dim3(256), 0, stream, qg, kg, part);
  hipLaunchKernelGGL(k2_softmax, dim3(64, 4), dim3(256), 0, stream,
                     part, ah, al, qn2, kn2, tt);
  hipLaunchKernelGGL(k3_av, dim3(36, 64), dim3(256), 0, stream, ah, al, vg, og);
  hipLaunchKernelGGL(k4_fuse, dim3(4, 1024), dim3(256), 0, stream, og, wf, bfu, out);
}

// Round 16
// 239.181 us; speedup vs baseline: 1.0527x; 1.0470x over previous
//
#include <hip/hip_runtime.h>
#include <hip/hip_bf16.h>
#include <stdint.h>

// Problem constants
#define BB     8
#define CC     128
#define HW     9216      // 96*96
#define NHEAD  8
#define HD     64
#define NCH    16        // gram n-chunks
#define CHUNK  576       // HW/NCH
#define KPAD   68        // gram LDS row (ushort): 64 px + 4 pad = 136B stride
#define VTPAD  68        // k3 v^T LDS row (ushort): 64 e + 4 pad = 136B stride

typedef __hip_bfloat16 bf16;
using frag16 = __attribute__((ext_vector_type(8))) short;  // 8 bf16 (4 VGPRs)
using f32x4  = __attribute__((ext_vector_type(4))) float;

__device__ __forceinline__ float b2f(bf16 v) { return __bfloat162float(v); }
__device__ __forceinline__ bf16  f2b(float v) { return __float2bfloat16(v); }

__device__ __forceinline__ float lo2f(unsigned int u) {
  union { unsigned int i; float f; } c; c.i = u << 16; return c.f;
}
__device__ __forceinline__ float hi2f(unsigned int u) {
  union { unsigned int i; float f; } c; c.i = u & 0xffff0000u; return c.f;
}

__device__ __forceinline__ unsigned int pack2(float a, float b) {
  union { __hip_bfloat162 h2; unsigned int u; } c;
  c.h2 = __float22bfloat162_rn(make_float2(a, b));   // v_cvt_pk_bf16_f32
  return c.u;
}

// LDS frag read from 8B-aligned address
__device__ __forceinline__ frag16 ldsfrag(const unsigned short* p) {
  uint2 lo = *(const uint2*)p;
  uint2 hi = *(const uint2*)(p + 4);
  union { unsigned int u[4]; frag16 f; } c;
  c.u[0] = lo.x; c.u[1] = lo.y; c.u[2] = hi.x; c.u[3] = hi.y;
  return c.f;
}
// LDS 16B store as two 8B stores (8B-aligned dst)
__device__ __forceinline__ void ldsst(unsigned short* p, uint4 v) {
  *(uint2*)p = make_uint2(v.x, v.y);
  *(uint2*)(p + 4) = make_uint2(v.z, v.w);
}

// Shared staging for k1: zero-pad halo only (interior fully overwritten), then stage plane.
__device__ __forceinline__ void stage_plane(float* xs, const float* xp, int tid) {
  const float4 z4 = make_float4(0.f, 0.f, 0.f, 0.f);
  for (int i = tid; i < 98; i += 256) *(float4*)&xs[i * 100] = z4;        // cols 0..3
  for (int i = tid; i < 24; i += 256) *(float4*)&xs[4 + i * 4] = z4;     // row 0
  for (int i = tid; i < 25; i += 256) *(float4*)&xs[9704 + i * 4] = z4;  // row 97 + guard
  for (int i = tid; i < 96 * 24; i += 256) {
    int y = i / 24, g4 = i - y * 24;
    ((float4*)(xs + (y + 1) * 100 + 4))[g4] = ((const float4*)(xp + y * 96))[g4];
  }
}

// ---------------------------------------------------------------- K1: qkv depthwise conv + q/k norms
// block = (b, c), full 96x96 plane in LDS, single dispatch (merged back).
__global__ __launch_bounds__(256) void k1_qkv(
    const float* __restrict__ x, const float* __restrict__ wq,
    const float* __restrict__ bq,
    bf16* __restrict__ qg, bf16* __restrict__ kg, bf16* __restrict__ vg,
    float* __restrict__ qn2, float* __restrict__ kn2) {
  __shared__ float xs[98 * 100 + 4];
  __shared__ float red[32];
  int tid = threadIdx.x;
  int wave = tid >> 6, lane = tid & 63;
  int b = blockIdx.x >> 7, c = blockIdx.x & 127;
  const float* xp = x + (size_t)(b * CC + c) * HW;
  stage_plane(xs, xp, tid);
  __syncthreads();

  int half = c >> 6, d = c & 63;
  int nidx[8];
  size_t basep[12];
#pragma unroll
  for (int j = 0; j < 12; ++j) {
    int e = j & 3;
    int h = e * 2 + half;
    int ni = (b * NHEAD + h) * HD + d;
    if (j < 8) nidx[j] = ni;
    basep[j] = (size_t)ni * HW;
  }
  const float* wrow = wq + c * 108;
  const float* brow = bq + c * 12;

  float ssq[8];
#pragma unroll
  for (int j = 0; j < 8; ++j) ssq[j] = 0.f;

#pragma unroll 1
  for (int it = 0; it < 5; ++it) {
    int u = it * 256 + tid;
    if (u < 1152) {
      int ly = u / 12;
      int x8 = (u - ly * 12) * 8;
      int p0 = ly * 96 + x8;
      float w10[3][10];
#pragma unroll
      for (int ky = 0; ky < 3; ++ky) {
        int basea = (ly + ky) * 100 + 4 + x8;
        float4 M0 = *(const float4*)&xs[basea];
        float4 M1 = *(const float4*)&xs[basea + 4];
        w10[ky][0] = xs[basea - 1];
        w10[ky][1] = M0.x; w10[ky][2] = M0.y; w10[ky][3] = M0.z; w10[ky][4] = M0.w;
        w10[ky][5] = M1.x; w10[ky][6] = M1.y; w10[ky][7] = M1.z; w10[ky][8] = M1.w;
        w10[ky][9] = xs[basea + 8];
      }
#pragma unroll
      for (int j = 0; j < 12; ++j) {
        float bias = brow[j];
        float a[8];
#pragma unroll
        for (int p = 0; p < 8; ++p) a[p] = bias;
#pragma unroll
        for (int ky = 0; ky < 3; ++ky)
#pragma unroll
          for (int kx = 0; kx < 3; ++kx) {
            float w = wrow[j * 9 + ky * 3 + kx];
#pragma unroll
            for (int p = 0; p < 8; ++p)
              a[p] = fmaf(w, w10[ky][kx + p], a[p]);
          }
        uint4 st;
        st.x = pack2(a[0], a[1]); st.y = pack2(a[2], a[3]);
        st.z = pack2(a[4], a[5]); st.w = pack2(a[6], a[7]);
        if (j < 4)      *(uint4*)(qg + basep[j] + p0) = st;
        else if (j < 8) *(uint4*)(kg + basep[j] + p0) = st;
        else            *(uint4*)(vg + basep[j] + p0) = st;
        if (j < 8) {
          float s2 = 0.f;
#pragma unroll
          for (int p = 0; p < 8; ++p) s2 = fmaf(a[p], a[p], s2);
          ssq[j] += s2;
        }
      }
    }
  }
#pragma unroll
  for (int j = 0; j < 8; ++j) {
    float v = ssq[j];
#pragma unroll
    for (int off = 32; off > 0; off >>= 1) v += __shfl_down(v, off);
    if (lane == 0) red[wave * 8 + j] = v;
  }
  __syncthreads();
  if (tid < 8) {
    float s = red[tid] + red[8 + tid] + red[16 + tid] + red[24 + tid];
    if (tid < 4) qn2[nidx[tid]] = s;
    else         kn2[nidx[tid]] = s;
  }
}

// ---------------------------------------------------------------- K2a: gram partials via MFMA, LDS-staged
// R7-verified BK=64 version (ran inside the 232.9us best total).
__global__ __launch_bounds__(256) void k2_gram(
    const bf16* __restrict__ qg, const bf16* __restrict__ kg,
    float* __restrict__ part) {
  __shared__ unsigned short sq[2][64 * KPAD];   // 17408 B
  __shared__ unsigned short sk[2][64 * KPAD];   // 17408 B
  int tid = threadIdx.x;
  int wave = tid >> 6;           // 0..3 -> d-tile
  int lane = tid & 63;
  int chunk = blockIdx.x;        // 0..15
  int bh = blockIdx.y;           // 0..63
  const size_t base = (size_t)bh * HD * HW;
  int n0 = chunk * CHUNK;

  int srow = tid >> 3;           // 0..31
  int sseg = tid & 7;            // 0..7 (8px each)
  const bf16* qs0 = qg + base + (size_t)srow * HW + n0 + sseg * 8;
  const bf16* qs1 = qs0 + (size_t)32 * HW;
  const bf16* ks0 = kg + base + (size_t)srow * HW + n0 + sseg * 8;
  const bf16* ks1 = ks0 + (size_t)32 * HW;
  int d0 = srow * KPAD + sseg * 8;
  int d1 = (srow + 32) * KPAD + sseg * 8;

  int m = lane & 15;
  int k8 = lane >> 4;            // 0..3
  int arow = wave * 16 + m;

  f32x4 acc0 = {0.f, 0.f, 0.f, 0.f}, acc1 = acc0, acc2 = acc0, acc3 = acc0;

  uint4 rq0 = *(const uint4*)(qs0);
  uint4 rq1 = *(const uint4*)(qs1);
  uint4 rk0 = *(const uint4*)(ks0);
  uint4 rk1 = *(const uint4*)(ks1);
  ldsst(&sq[0][d0], rq0); ldsst(&sq[0][d1], rq1);
  ldsst(&sk[0][d0], rk0); ldsst(&sk[0][d1], rk1);
  __syncthreads();

#pragma unroll 1
  for (int s = 0; s < 9; ++s) {
    if (s < 8) {                       // issue next-step loads early (T14)
      int off = (s + 1) * 64;
      rq0 = *(const uint4*)(qs0 + off);
      rq1 = *(const uint4*)(qs1 + off);
      rk0 = *(const uint4*)(ks0 + off);
      rk1 = *(const uint4*)(ks1 + off);
    }
    const unsigned short* sqc = sq[s & 1];
    const unsigned short* skc = sk[s & 1];
#pragma unroll
    for (int kk = 0; kk < 2; ++kk) {
      int co = kk * 32 + k8 * 8;
      frag16 a  = ldsfrag(&sqc[arow * KPAD + co]);
      frag16 b0 = ldsfrag(&skc[(m +  0) * KPAD + co]);
      frag16 b1 = ldsfrag(&skc[(m + 16) * KPAD + co]);
      frag16 b2 = ldsfrag(&skc[(m + 32) * KPAD + co]);
      frag16 b3 = ldsfrag(&skc[(m + 48) * KPAD + co]);
      acc0 = __builtin_amdgcn_mfma_f32_16x16x32_bf16(a, b0, acc0, 0, 0, 0);
      acc1 = __builtin_amdgcn_mfma_f32_16x16x32_bf16(a, b1, acc1, 0, 0, 0);
      acc2 = __builtin_amdgcn_mfma_f32_16x16x32_bf16(a, b2, acc2, 0, 0, 0);
      acc3 = __builtin_amdgcn_mfma_f32_16x16x32_bf16(a, b3, acc3, 0, 0, 0);
    }
    if (s < 8) {
      int nb = (s + 1) & 1;
      ldsst(&sq[nb][d0], rq0); ldsst(&sq[nb][d1], rq1);
      ldsst(&sk[nb][d0], rk0); ldsst(&sk[nb][d1], rk1);
      __syncthreads();
    }
  }

  // C/D layout: row(d) = (lane>>4)*4 + r, col(e) = lane&15
  float* po = part + (size_t)(bh * NCH + chunk) * 4096;
  int dr = wave * 16 + (lane >> 4) * 4;
  int e0 = lane & 15;
#pragma unroll
  for (int r = 0; r < 4; ++r) {
    po[(dr + r) * 64 +  0 + e0] = acc0[r];
    po[(dr + r) * 64 + 16 + e0] = acc1[r];
    po[(dr + r) * 64 + 32 + e0] = acc2[r];
    po[(dr + r) * 64 + 48 + e0] = acc3[r];
  }
}

// ---------------------------------------------------------------- K2b: reduce partials + normalize + softmax
__global__ __launch_bounds__(256) void k2_softmax(
    const float* __restrict__ part, bf16* __restrict__ ah, bf16* __restrict__ al,
    const float* __restrict__ qn2, const float* __restrict__ kn2,
    const float* __restrict__ t_f) {
  __shared__ float kns[64];
  int bh = blockIdx.x;
  int dq = blockIdx.y;
  int tid = threadIdx.x;
  if (tid < 64) kns[tid] = fmaxf(sqrtf(kn2[bh * 64 + tid]), 1e-12f);
  __syncthreads();
  int d  = dq * 16 + (tid >> 4);
  int e0 = (tid & 15) * 4;

  const float* pb = part + (size_t)bh * NCH * 4096 + d * 64 + e0;
  float4 s = make_float4(0.f, 0.f, 0.f, 0.f);
#pragma unroll
  for (int ch = 0; ch < NCH; ++ch) {
    float4 g = *(const float4*)&pb[ch * 4096];
    s.x += g.x; s.y += g.y; s.z += g.z; s.w += g.w;
  }
  float v[4] = {s.x, s.y, s.z, s.w};
  float sc = t_f[bh & 7] / fmaxf(sqrtf(qn2[bh * 64 + d]), 1e-12f);
  float m = -1e30f;
#pragma unroll
  for (int j = 0; j < 4; ++j) {
    v[j] = v[j] * sc / kns[e0 + j];
    m = fmaxf(m, v[j]);
  }
  m = fmaxf(m, __shfl_xor(m, 1));
  m = fmaxf(m, __shfl_xor(m, 2));
  m = fmaxf(m, __shfl_xor(m, 4));
  m = fmaxf(m, __shfl_xor(m, 8));
  float ssum = 0.f;
#pragma unroll
  for (int j = 0; j < 4; ++j) { v[j] = __expf(v[j] - m); ssum += v[j]; }
  ssum += __shfl_xor(ssum, 1);
  ssum += __shfl_xor(ssum, 2);
  ssum += __shfl_xor(ssum, 4);
  ssum += __shfl_xor(ssum, 8);
  float inv = 1.f / ssum;
  unsigned short hi16[4], lo16[4];
#pragma unroll
  for (int j = 0; j < 4; ++j) {
    float p = v[j] * inv;
    bf16 hi = f2b(p);
    float lo = p - b2f(hi);
    bf16 lov = f2b(lo);
    hi16[j] = *(unsigned short*)&hi;
    lo16[j] = *(unsigned short*)&lov;
  }
  const size_t base = (size_t)bh * 4096 + d * 64 + e0;
  *(ushort4*)(ah + base) = *(ushort4*)&hi16[0];
  *(ushort4*)(al + base) = *(ushort4*)&lo16[0];
}

// ---------------------------------------------------------------- K3: o = attn @ v via MFMA
// v4: operand-swapped MFMA computes o^T tiles: acc = mfma(v_frag, attn_frag) puts
// n on output ROWS ((lane>>4)*4+r = 4 consecutive n per lane) -> pack 4 bf16, ONE 8B
// store per acc (16 stores/thread, was 64 scalar). attn frags = B operand, loaded once
// per block and reused across 2 chunks (grid 18x64); chunk1 v reg-prefetched during
// chunk0 MFMA/stores (T14, k2_gram's verified pattern).
__global__ __launch_bounds__(256) void k3_av(
    const bf16* __restrict__ ah, const bf16* __restrict__ al,
    const bf16* __restrict__ vg, bf16* __restrict__ og) {
  __shared__ unsigned short vt[256 * VTPAD];   // 34816 B: v^T tile [n_local][e]
  int tid = threadIdx.x;
  int wave = tid >> 6, lane = tid & 63;
  int cx = blockIdx.x;      // 0..17 (2 chunks of 256 px each)
  int bh = blockIdx.y;      // 0..63
  int b = bh >> 3, h = bh & 7;
  int n0 = cx * 512;
  int m = lane & 15;
  int k8 = (lane >> 4) * 8;
  int nwbase = wave * 64;

  // attn fragments (B operand), hoisted: global latency hides under staging+barrier
  const bf16* ahp = ah + (size_t)bh * 4096;
  const bf16* alp = al + (size_t)bh * 4096;
  frag16 b_hi[4][2], b_lo[4][2];
#pragma unroll
  for (int dt = 0; dt < 4; ++dt)
#pragma unroll
    for (int kh = 0; kh < 2; ++kh) {
      b_hi[dt][kh] = *(const frag16*)(ahp + (dt * 16 + m) * 64 + kh * 32 + k8);
      b_lo[dt][kh] = *(const frag16*)(alp + (dt * 16 + m) * 64 + kh * 32 + k8);
    }

  // staging unit coords (v3-verified transpose)
  int ueq = tid & 15, unq = tid >> 4;       // reused each it with +64 n... per-it below
  (void)ueq; (void)unq;
  const bf16* vbase = vg + (size_t)bh * HD * HW;

  // stage chunk 0
#pragma unroll
  for (int it = 0; it < 4; ++it) {
    int u = it * 256 + tid;
    int eq = u & 15, nq = u >> 4;
    const bf16* src = vbase + n0 + (size_t)(eq * 4) * HW + nq * 4;
    ushort4 r0 = *(const ushort4*)(src);
    ushort4 r1 = *(const ushort4*)(src + HW);
    ushort4 r2 = *(const ushort4*)(src + 2 * HW);
    ushort4 r3 = *(const ushort4*)(src + (size_t)3 * HW);
    unsigned short* dst = &vt[(nq * 4) * VTPAD + eq * 4];
    *(ushort4*)(dst)             = make_ushort4(r0.x, r1.x, r2.x, r3.x);
    *(ushort4*)(dst + VTPAD)     = make_ushort4(r0.y, r1.y, r2.y, r3.y);
    *(ushort4*)(dst + 2 * VTPAD) = make_ushort4(r0.z, r1.z, r2.z, r3.z);
    *(ushort4*)(dst + 3 * VTPAD) = make_ushort4(r0.w, r1.w, r2.w, r3.w);
  }
  __syncthreads();

  int cc0 = (h & 1) * 256 + (h >> 1);
  bf16* ob = og + (size_t)b * 512 * HW;
  int q4 = (lane >> 4) * 4;

  ushort4 pf[4][4];    // chunk-1 prefetch (static-indexed, fully unrolled)

#pragma unroll 1
  for (int s = 0; s < 2; ++s) {
    if (s == 0) {
      // T14: issue chunk-1 loads early; consumed after the post-MFMA barrier
#pragma unroll
      for (int it = 0; it < 4; ++it) {
        int u = it * 256 + tid;
        int eq = u & 15, nq = u >> 4;
        const bf16* src = vbase + n0 + 256 + (size_t)(eq * 4) * HW + nq * 4;
        pf[it][0] = *(const ushort4*)(src);
        pf[it][1] = *(const ushort4*)(src + HW);
        pf[it][2] = *(const ushort4*)(src + 2 * HW);
        pf[it][3] = *(const ushort4*)(src + (size_t)3 * HW);
      }
    }
    // MFMA: o^T tiles — A = v^T rows (n), B = attn rows (d)
    f32x4 acc[4][4];
#pragma unroll
    for (int nt = 0; nt < 4; ++nt)
#pragma unroll
      for (int dt = 0; dt < 4; ++dt) acc[nt][dt] = {0.f, 0.f, 0.f, 0.f};

#pragma unroll
    for (int nt = 0; nt < 4; ++nt) {
      int nl = nwbase + nt * 16 + m;
      frag16 af0 = ldsfrag(&vt[nl * VTPAD + 0 + k8]);
      frag16 af1 = ldsfrag(&vt[nl * VTPAD + 32 + k8]);
#pragma unroll
      for (int dt = 0; dt < 4; ++dt) {
        acc[nt][dt] = __builtin_amdgcn_mfma_f32_16x16x32_bf16(af0, b_hi[dt][0], acc[nt][dt], 0, 0, 0);
        acc[nt][dt] = __builtin_amdgcn_mfma_f32_16x16x32_bf16(af0, b_lo[dt][0], acc[nt][dt], 0, 0, 0);
        acc[nt][dt] = __builtin_amdgcn_mfma_f32_16x16x32_bf16(af1, b_hi[dt][1], acc[nt][dt], 0, 0, 0);
        acc[nt][dt] = __builtin_amdgcn_mfma_f32_16x16x32_bf16(af1, b_lo[dt][1], acc[nt][dt], 0, 0, 0);
      }
    }
    // stores: one 8B packed store per acc tile; 4 consecutive n per lane
    int ns0 = n0 + s * 256 + nwbase + q4;
#pragma unroll
    for (int nt = 0; nt < 4; ++nt)
#pragma unroll
      for (int dt = 0; dt < 4; ++dt) {
        int d = dt * 16 + m;
        uint2 st = make_uint2(pack2(acc[nt][dt][0], acc[nt][dt][1]),
                              pack2(acc[nt][dt][2], acc[nt][dt][3]));
        *(uint2*)(ob + (size_t)(cc0 + d * 4) * HW + ns0 + nt * 16) = st;
      }
    if (s == 0) {
      __syncthreads();   // all waves done reading chunk-0 vt
#pragma unroll
      for (int it = 0; it < 4; ++it) {
        int u = it * 256 + tid;
        int eq = u & 15, nq = u >> 4;
        unsigned short* dst = &vt[(nq * 4) * VTPAD + eq * 4];
        ushort4 r0 = pf[it][0], r1 = pf[it][1], r2 = pf[it][2], r3 = pf[it][3];
        *(ushort4*)(dst)             = make_ushort4(r0.x, r1.x, r2.x, r3.x);
        *(ushort4*)(dst + VTPAD)     = make_ushort4(r0.y, r1.y, r2.y, r3.y);
        *(ushort4*)(dst + 2 * VTPAD) = make_ushort4(r0.z, r1.z, r2.z, r3.z);
        *(ushort4*)(dst + 3 * VTPAD) = make_ushort4(r0.w, r1.w, r2.w, r3.w);
      }
      __syncthreads();   // chunk-1 vt visible
    }
  }
}

// ---------------------------------------------------------------- K4: fused grouped 3x3 conv (4 in-ch -> 1 out-ch)
// bf16 channel-interleaved cells (verified ~22us): 20.8 KB, 7 blocks/CU.
__global__ __launch_bounds__(256) void k4_fuse(
    const bf16* __restrict__ og, const float* __restrict__ wf,
    const float* __restrict__ bfu, float* __restrict__ out) {
  __shared__ unsigned short cells[26 * 100 * 4];   // 20800 B
  int tid = threadIdx.x;
  int tile = blockIdx.x;                // 0..3
  int bc = blockIdx.y;                  // 0..1023
  int b = bc >> 7, c = bc & 127;
  int r0 = tile * 24 - 1;
  const uint2 z2 = make_uint2(0u, 0u);
  for (int i = tid; i < 52; i += 256) {
    int rr = i >> 1, cc = (i & 1) ? 98 : 1;
    *(uint2*)&cells[(rr * 100 + cc) * 4] = z2;
  }
  const uint4 z4 = make_uint4(0u, 0u, 0u, 0u);
  if (r0 < 0)
    for (int i = tid; i < 48; i += 256) *(uint4*)&cells[(0 * 100 + 2 + i * 2) * 4] = z4;
  if (r0 + 25 >= 96)
    for (int i = tid; i < 48; i += 256) *(uint4*)&cells[(25 * 100 + 2 + i * 2) * 4] = z4;
  const bf16* op = og + (size_t)(b * 512 + c * 4) * HW;
  for (int u = tid; u < 26 * 48; u += 256) {
    int rr = u / 48, pr = u - rr * 48;
    int gr = r0 + rr;
    if (gr >= 0 && gr < 96) {
      int gp = gr * 96 + pr * 2;
      unsigned int A = *(const unsigned int*)(op + gp);
      unsigned int B = *(const unsigned int*)(op + HW + gp);
      unsigned int C = *(const unsigned int*)(op + 2 * HW + gp);
      unsigned int D = *(const unsigned int*)(op + (size_t)3 * HW + gp);
      uint4 w;
      w.x = (A & 0xffffu) | (B << 16);          // px0: ch0|ch1
      w.y = (C & 0xffffu) | (D << 16);          // px0: ch2|ch3
      w.z = (A >> 16) | (B & 0xffff0000u);      // px1: ch0|ch1
      w.w = (C >> 16) | (D & 0xffff0000u);      // px1: ch2|ch3
      *(uint4*)&cells[(rr * 100 + 2 + pr * 2) * 4] = w;
    }
  }
  __syncthreads();
  const float* wrow = wf + c * 36;      // uniform -> s_load
  float bias = bfu[c];
  float* outp = out + (size_t)(b * CC + c) * HW + tile * 24 * 96;
#pragma unroll
  for (int pi = 0; pi < 9; ++pi) {
    int p = pi * 256 + tid;
    int ry = p / 96, x = p - ry * 96;
    float a0 = bias, a1 = 0.f, a2 = 0.f, a3 = 0.f;
#pragma unroll
    for (int ky = 0; ky < 3; ++ky) {
      int basec = (ry + ky) * 100 + 1 + x;
#pragma unroll
      for (int kx = 0; kx < 3; ++kx) {
        uint2 cc2 = *(const uint2*)&cells[(basec + kx) * 4];   // b64, 2 lanes/bank
        a0 = fmaf(wrow[0 + ky * 3 + kx],  lo2f(cc2.x), a0);
        a1 = fmaf(wrow[9 + ky * 3 + kx],  hi2f(cc2.x), a1);
        a2 = fmaf(wrow[18 + ky * 3 + kx], lo2f(cc2.y), a2);
        a3 = fmaf(wrow[27 + ky * 3 + kx], hi2f(cc2.y), a3);
      }
    }
    outp[p] = (a0 + a1) + (a2 + a3);
  }
}

// ---------------------------------------------------------------- launcher
extern "C" void kernel_launch(void* const* d_in, const int* in_sizes, int n_in,
                              void* d_out, int out_size, void* d_ws, size_t ws_size,
                              hipStream_t stream) {
  (void)in_sizes; (void)n_in; (void)out_size; (void)ws_size;
  const float* x   = (const float*)d_in[0];
  const float* wq  = (const float*)d_in[1];
  const float* bq  = (const float*)d_in[2];
  const float* tt  = (const float*)d_in[3];
  const float* wf  = (const float*)d_in[4];
  const float* bfu = (const float*)d_in[5];

  // workspace layout (~245 MB)
  char* ws = (char*)d_ws;
  bf16*  qg    = (bf16*)(ws + 0);                 // 75497472 B, later aliased by og
  bf16*  kg    = (bf16*)(ws + 75497472);          // 75497472 B
  bf16*  vg    = (bf16*)(ws + 150994944);         // 75497472 B
  float* part  = (float*)(ws + 226492416);        // 16777216 B
  bf16*  ah    = (bf16*)(ws + 243269632);         // 524288 B
  bf16*  al    = (bf16*)(ws + 243793920);         // 524288 B
  float* qn2   = (float*)(ws + 244318208);        // 16384 B
  float* kn2   = (float*)(ws + 244334592);        // 16384 B
  bf16*  og    = qg;                              // q is dead after k2_gram
  float* out   = (float*)d_out;

  hipLaunchKernelGGL(k1_qkv, dim3(1024), dim3(256), 0, stream,
                     x, wq, bq, qg, kg, vg, qn2, kn2);
  hipLaunchKernelGGL(k2_gram, dim3(NCH, 64), dim3(256), 0, stream, qg, kg, part);
  hipLaunchKernelGGL(k2_softmax, dim3(64, 4), dim3(256), 0, stream,
                     part, ah, al, qn2, kn2, tt);
  hipLaunchKernelGGL(k3_av, dim3(18, 64), dim3(256), 0, stream, ah, al, vg, og);
  hipLaunchKernelGGL(k4_fuse, dim3(4, 1024), dim3(256), 0, stream, og, wf, bfu, out);
}

// Round 17
// 229.170 us; speedup vs baseline: 1.0986x; 1.0437x over previous
//
#include <hip/hip_runtime.h>
#include <hip/hip_bf16.h>
#include <stdint.h>

// Problem constants
#define BB     8
#define CC     128
#define HW     9216      // 96*96
#define NHEAD  8
#define HD     64
#define NCH    16        // gram n-chunks
#define CHUNK  576       // HW/NCH
#define BK     32        // gram K-step (px)
#define K2PAD  36        // gram LDS row (ushort): 32 px + 4 pad = 72B stride

typedef __hip_bfloat16 bf16;
using frag16 = __attribute__((ext_vector_type(8))) short;  // 8 bf16 (4 VGPRs)
using f32x4  = __attribute__((ext_vector_type(4))) float;

__device__ __forceinline__ float b2f(bf16 v) { return __bfloat162float(v); }
__device__ __forceinline__ bf16  f2b(float v) { return __float2bfloat16(v); }

__device__ __forceinline__ float lo2f(unsigned int u) {
  union { unsigned int i; float f; } c; c.i = u << 16; return c.f;
}
__device__ __forceinline__ float hi2f(unsigned int u) {
  union { unsigned int i; float f; } c; c.i = u & 0xffff0000u; return c.f;
}

__device__ __forceinline__ unsigned int pack2(float a, float b) {
  union { __hip_bfloat162 h2; unsigned int u; } c;
  c.h2 = __float22bfloat162_rn(make_float2(a, b));   // v_cvt_pk_bf16_f32
  return c.u;
}

// LDS frag read from 8B-aligned address (rows are 72B-strided)
__device__ __forceinline__ frag16 ldsfrag(const unsigned short* p) {
  uint2 lo = *(const uint2*)p;
  uint2 hi = *(const uint2*)(p + 4);
  union { unsigned int u[4]; frag16 f; } c;
  c.u[0] = lo.x; c.u[1] = lo.y; c.u[2] = hi.x; c.u[3] = hi.y;
  return c.f;
}
// LDS 16B store as two 8B stores (8B-aligned dst)
__device__ __forceinline__ void ldsst(unsigned short* p, uint4 v) {
  *(uint2*)p = make_uint2(v.x, v.y);
  *(uint2*)(p + 4) = make_uint2(v.z, v.w);
}

// Shared staging for k1: zero-pad halo only (interior fully overwritten), then stage plane.
__device__ __forceinline__ void stage_plane(float* xs, const float* xp, int tid) {
  const float4 z4 = make_float4(0.f, 0.f, 0.f, 0.f);
  for (int i = tid; i < 98; i += 256) *(float4*)&xs[i * 100] = z4;        // cols 0..3
  for (int i = tid; i < 24; i += 256) *(float4*)&xs[4 + i * 4] = z4;     // row 0
  for (int i = tid; i < 25; i += 256) *(float4*)&xs[9704 + i * 4] = z4;  // row 97 + guard
  for (int i = tid; i < 96 * 24; i += 256) {
    int y = i / 24, g4 = i - y * 24;
    ((float4*)(xs + (y + 1) * 100 + 4))[g4] = ((const float4*)(xp + y * 96))[g4];
  }
}

// ---------------------------------------------------------------- K1: qkv depthwise conv + q/k norms
// block = (b, c), full 96x96 plane in LDS. 8 px/thread units (measured ~53-62us
// depending on session; write-stream + VALU hybrid, near its pattern ceiling).
__global__ __launch_bounds__(256) void k1_qkv(
    const float* __restrict__ x, const float* __restrict__ wq,
    const float* __restrict__ bq,
    bf16* __restrict__ qg, bf16* __restrict__ kg, bf16* __restrict__ vg,
    float* __restrict__ qn2, float* __restrict__ kn2) {
  __shared__ float xs[98 * 100 + 4];
  __shared__ float red[32];
  int tid = threadIdx.x;
  int wave = tid >> 6, lane = tid & 63;
  int b = blockIdx.x >> 7, c = blockIdx.x & 127;
  const float* xp = x + (size_t)(b * CC + c) * HW;
  stage_plane(xs, xp, tid);
  __syncthreads();

  int half = c >> 6, d = c & 63;
  int nidx[8];
  size_t basep[12];
#pragma unroll
  for (int j = 0; j < 12; ++j) {
    int e = j & 3;
    int h = e * 2 + half;
    int ni = (b * NHEAD + h) * HD + d;
    if (j < 8) nidx[j] = ni;
    basep[j] = (size_t)ni * HW;
  }
  const float* wrow = wq + c * 108;
  const float* brow = bq + c * 12;

  float ssq[8];
#pragma unroll
  for (int j = 0; j < 8; ++j) ssq[j] = 0.f;

#pragma unroll 1
  for (int it = 0; it < 5; ++it) {
    int u = it * 256 + tid;
    if (u < 1152) {
      int ly = u / 12;
      int x8 = (u - ly * 12) * 8;
      int p0 = ly * 96 + x8;
      float w10[3][10];
#pragma unroll
      for (int ky = 0; ky < 3; ++ky) {
        int basea = (ly + ky) * 100 + 4 + x8;
        float4 M0 = *(const float4*)&xs[basea];
        float4 M1 = *(const float4*)&xs[basea + 4];
        w10[ky][0] = xs[basea - 1];
        w10[ky][1] = M0.x; w10[ky][2] = M0.y; w10[ky][3] = M0.z; w10[ky][4] = M0.w;
        w10[ky][5] = M1.x; w10[ky][6] = M1.y; w10[ky][7] = M1.z; w10[ky][8] = M1.w;
        w10[ky][9] = xs[basea + 8];
      }
#pragma unroll
      for (int j = 0; j < 12; ++j) {
        float bias = brow[j];
        float a[8];
#pragma unroll
        for (int p = 0; p < 8; ++p) a[p] = bias;
#pragma unroll
        for (int ky = 0; ky < 3; ++ky)
#pragma unroll
          for (int kx = 0; kx < 3; ++kx) {
            float w = wrow[j * 9 + ky * 3 + kx];
#pragma unroll
            for (int p = 0; p < 8; ++p)
              a[p] = fmaf(w, w10[ky][kx + p], a[p]);
          }
        uint4 st;
        st.x = pack2(a[0], a[1]); st.y = pack2(a[2], a[3]);
        st.z = pack2(a[4], a[5]); st.w = pack2(a[6], a[7]);
        if (j < 4)      *(uint4*)(qg + basep[j] + p0) = st;
        else if (j < 8) *(uint4*)(kg + basep[j] + p0) = st;
        else            *(uint4*)(vg + basep[j] + p0) = st;
        if (j < 8) {
          float s2 = 0.f;
#pragma unroll
          for (int p = 0; p < 8; ++p) s2 = fmaf(a[p], a[p], s2);
          ssq[j] += s2;
        }
      }
    }
  }
#pragma unroll
  for (int j = 0; j < 8; ++j) {
    float v = ssq[j];
#pragma unroll
    for (int off = 32; off > 0; off >>= 1) v += __shfl_down(v, off);
    if (lane == 0) red[wave * 8 + j] = v;
  }
  __syncthreads();
  if (tid < 8) {
    float s = red[tid] + red[8 + tid] + red[16 + tid] + red[24 + tid];
    if (tid < 4) qn2[nidx[tid]] = s;
    else         kn2[nidx[tid]] = s;
  }
}

// ---------------------------------------------------------------- K2a: gram partials via MFMA, LDS-staged
// BK=32 double-buffered (R11 best-total config): LDS 18.4 KB -> 8 blocks/CU.
// 18 steps/chunk; per step: 1 uint4 stage per matrix per thread, 5 frag reads,
// 4 MFMA; dbuf/T14/single-barrier order.
__global__ __launch_bounds__(256) void k2_gram(
    const bf16* __restrict__ qg, const bf16* __restrict__ kg,
    float* __restrict__ part) {
  __shared__ unsigned short sq[2][64 * K2PAD];   // 4608 B each
  __shared__ unsigned short sk[2][64 * K2PAD];
  int tid = threadIdx.x;
  int wave = tid >> 6;           // 0..3 -> d-tile
  int lane = tid & 63;
  int chunk = blockIdx.x;        // 0..15
  int bh = blockIdx.y;           // 0..63
  const size_t base = (size_t)bh * HD * HW;
  int n0 = chunk * CHUNK;

  // staging coords: one uint4 (8px) per thread per matrix per step
  int srow = tid >> 2;           // 0..63
  int sseg = tid & 3;            // 0..3 (8px each)
  const bf16* qs = qg + base + (size_t)srow * HW + n0 + sseg * 8;
  const bf16* ks = kg + base + (size_t)srow * HW + n0 + sseg * 8;
  int dst = srow * K2PAD + sseg * 8;

  int m = lane & 15;
  int k8 = lane >> 4;            // 0..3
  int arow = wave * 16 + m;

  f32x4 acc0 = {0.f, 0.f, 0.f, 0.f}, acc1 = acc0, acc2 = acc0, acc3 = acc0;

  // prologue: stage step 0
  uint4 rq = *(const uint4*)(qs);
  uint4 rk = *(const uint4*)(ks);
  ldsst(&sq[0][dst], rq); ldsst(&sk[0][dst], rk);
  __syncthreads();

#pragma unroll 1
  for (int s = 0; s < 18; ++s) {
    if (s < 17) {                      // issue next-step loads early (T14)
      int off = (s + 1) * BK;
      rq = *(const uint4*)(qs + off);
      rk = *(const uint4*)(ks + off);
    }
    const unsigned short* sqc = sq[s & 1];
    const unsigned short* skc = sk[s & 1];
    int co = k8 * 8;
    frag16 a  = ldsfrag(&sqc[arow * K2PAD + co]);
    frag16 b0 = ldsfrag(&skc[(m +  0) * K2PAD + co]);
    frag16 b1 = ldsfrag(&skc[(m + 16) * K2PAD + co]);
    frag16 b2 = ldsfrag(&skc[(m + 32) * K2PAD + co]);
    frag16 b3 = ldsfrag(&skc[(m + 48) * K2PAD + co]);
    acc0 = __builtin_amdgcn_mfma_f32_16x16x32_bf16(a, b0, acc0, 0, 0, 0);
    acc1 = __builtin_amdgcn_mfma_f32_16x16x32_bf16(a, b1, acc1, 0, 0, 0);
    acc2 = __builtin_amdgcn_mfma_f32_16x16x32_bf16(a, b2, acc2, 0, 0, 0);
    acc3 = __builtin_amdgcn_mfma_f32_16x16x32_bf16(a, b3, acc3, 0, 0, 0);
    if (s < 17) {                      // write next buffer; single barrier per step
      int nb = (s + 1) & 1;
      ldsst(&sq[nb][dst], rq); ldsst(&sk[nb][dst], rk);
      __syncthreads();
    }
  }

  // C/D layout: row(d) = (lane>>4)*4 + r, col(e) = lane&15
  float* po = part + (size_t)(bh * NCH + chunk) * 4096;
  int dr = wave * 16 + (lane >> 4) * 4;
  int e0 = lane & 15;
#pragma unroll
  for (int r = 0; r < 4; ++r) {
    po[(dr + r) * 64 +  0 + e0] = acc0[r];
    po[(dr + r) * 64 + 16 + e0] = acc1[r];
    po[(dr + r) * 64 + 32 + e0] = acc2[r];
    po[(dr + r) * 64 + 48 + e0] = acc3[r];
  }
}

// ---------------------------------------------------------------- K2b: reduce partials + normalize + softmax
__global__ __launch_bounds__(256) void k2_softmax(
    const float* __restrict__ part, bf16* __restrict__ ah, bf16* __restrict__ al,
    const float* __restrict__ qn2, const float* __restrict__ kn2,
    const float* __restrict__ t_f) {
  __shared__ float kns[64];
  int bh = blockIdx.x;
  int dq = blockIdx.y;
  int tid = threadIdx.x;
  if (tid < 64) kns[tid] = fmaxf(sqrtf(kn2[bh * 64 + tid]), 1e-12f);
  __syncthreads();
  int d  = dq * 16 + (tid >> 4);
  int e0 = (tid & 15) * 4;

  const float* pb = part + (size_t)bh * NCH * 4096 + d * 64 + e0;
  float4 s = make_float4(0.f, 0.f, 0.f, 0.f);
#pragma unroll
  for (int ch = 0; ch < NCH; ++ch) {
    float4 g = *(const float4*)&pb[ch * 4096];
    s.x += g.x; s.y += g.y; s.z += g.z; s.w += g.w;
  }
  float v[4] = {s.x, s.y, s.z, s.w};
  float sc = t_f[bh & 7] / fmaxf(sqrtf(qn2[bh * 64 + d]), 1e-12f);
  float m = -1e30f;
#pragma unroll
  for (int j = 0; j < 4; ++j) {
    v[j] = v[j] * sc / kns[e0 + j];
    m = fmaxf(m, v[j]);
  }
  m = fmaxf(m, __shfl_xor(m, 1));
  m = fmaxf(m, __shfl_xor(m, 2));
  m = fmaxf(m, __shfl_xor(m, 4));
  m = fmaxf(m, __shfl_xor(m, 8));
  float ssum = 0.f;
#pragma unroll
  for (int j = 0; j < 4; ++j) { v[j] = __expf(v[j] - m); ssum += v[j]; }
  ssum += __shfl_xor(ssum, 1);
  ssum += __shfl_xor(ssum, 2);
  ssum += __shfl_xor(ssum, 4);
  ssum += __shfl_xor(ssum, 8);
  float inv = 1.f / ssum;
  unsigned short hi16[4], lo16[4];
#pragma unroll
  for (int j = 0; j < 4; ++j) {
    float p = v[j] * inv;
    bf16 hi = f2b(p);
    float lo = p - b2f(hi);
    bf16 lov = f2b(lo);
    hi16[j] = *(unsigned short*)&hi;
    lo16[j] = *(unsigned short*)&lov;
  }
  const size_t base = (size_t)bh * 4096 + d * 64 + e0;
  *(ushort4*)(ah + base) = *(ushort4*)&hi16[0];
  *(ushort4*)(al + base) = *(ushort4*)&lo16[0];
}

// ---------------------------------------------------------------- K3: o = attn @ v via MFMA
// ORIGINAL version (measured 41us — unbeaten across 3 LDS/operand-swap rewrites):
// A-frags hoisted, B-frags gathered directly from global (L1/L2-served), no LDS.
__global__ __launch_bounds__(256) void k3_av(
    const bf16* __restrict__ ah, const bf16* __restrict__ al,
    const bf16* __restrict__ vg, bf16* __restrict__ og) {
  int tid = threadIdx.x;
  int wave = tid >> 6, lane = tid & 63;
  int chunk = blockIdx.x;   // 0..35 (256 pixels each)
  int bh = blockIdx.y;      // 0..63
  int b = bh >> 3, h = bh & 7;
  int n0 = chunk * 256;
  int m = lane & 15;
  int k8 = (lane >> 4) * 8;
  int nwbase = wave * 64;

  const bf16* ahp = ah + (size_t)bh * 4096;
  const bf16* alp = al + (size_t)bh * 4096;
  frag16 a_hi[4][2], a_lo[4][2];
#pragma unroll
  for (int dt = 0; dt < 4; ++dt)
#pragma unroll
    for (int kh = 0; kh < 2; ++kh) {
      a_hi[dt][kh] = *(const frag16*)(ahp + (dt * 16 + m) * 64 + kh * 32 + k8);
      a_lo[dt][kh] = *(const frag16*)(alp + (dt * 16 + m) * 64 + kh * 32 + k8);
    }

  const bf16* vb = vg + (size_t)bh * HD * HW + n0 + nwbase + m;
  frag16 bfr[4][2];
#pragma unroll
  for (int kh = 0; kh < 2; ++kh)
#pragma unroll
    for (int j = 0; j < 8; ++j) {
      const bf16* vp = vb + (size_t)(kh * 32 + k8 + j) * HW;
      bfr[0][kh][j] = *(const short*)(vp);
      bfr[1][kh][j] = *(const short*)(vp + 16);
      bfr[2][kh][j] = *(const short*)(vp + 32);
      bfr[3][kh][j] = *(const short*)(vp + 48);
    }

  f32x4 acc[4][4];
#pragma unroll
  for (int dt = 0; dt < 4; ++dt)
#pragma unroll
    for (int nt = 0; nt < 4; ++nt) acc[dt][nt] = {0.f, 0.f, 0.f, 0.f};

#pragma unroll
  for (int nt = 0; nt < 4; ++nt)
#pragma unroll
    for (int kh = 0; kh < 2; ++kh)
#pragma unroll
      for (int dt = 0; dt < 4; ++dt) {
        acc[dt][nt] = __builtin_amdgcn_mfma_f32_16x16x32_bf16(a_hi[dt][kh], bfr[nt][kh], acc[dt][nt], 0, 0, 0);
        acc[dt][nt] = __builtin_amdgcn_mfma_f32_16x16x32_bf16(a_lo[dt][kh], bfr[nt][kh], acc[dt][nt], 0, 0, 0);
      }

  int cc0 = (h & 1) * 256 + (h >> 1);
  bf16* ob = og + (size_t)b * 512 * HW;
  int q4 = (lane >> 4) * 4;
#pragma unroll
  for (int dt = 0; dt < 4; ++dt)
#pragma unroll
    for (int nt = 0; nt < 4; ++nt) {
      int n = n0 + nwbase + nt * 16 + m;
#pragma unroll
      for (int r = 0; r < 4; ++r) {
        int d = dt * 16 + q4 + r;
        ob[(size_t)(cc0 + d * 4) * HW + n] = f2b(acc[dt][nt][r]);
      }
    }
}

// ---------------------------------------------------------------- K4: fused grouped 3x3 conv (4 in-ch -> 1 out-ch)
// bf16 channel-interleaved cells (verified ~22us): 20.8 KB, 7 blocks/CU,
// conflict-free staging (uint4 per 2 cells), b64 per tap.
__global__ __launch_bounds__(256) void k4_fuse(
    const bf16* __restrict__ og, const float* __restrict__ wf,
    const float* __restrict__ bfu, float* __restrict__ out) {
  __shared__ unsigned short cells[26 * 100 * 4];   // 20800 B
  int tid = threadIdx.x;
  int tile = blockIdx.x;                // 0..3
  int bc = blockIdx.y;                  // 0..1023
  int b = bc >> 7, c = bc & 127;
  int r0 = tile * 24 - 1;
  const uint2 z2 = make_uint2(0u, 0u);
  for (int i = tid; i < 52; i += 256) {
    int rr = i >> 1, cc = (i & 1) ? 98 : 1;
    *(uint2*)&cells[(rr * 100 + cc) * 4] = z2;
  }
  const uint4 z4 = make_uint4(0u, 0u, 0u, 0u);
  if (r0 < 0)
    for (int i = tid; i < 48; i += 256) *(uint4*)&cells[(0 * 100 + 2 + i * 2) * 4] = z4;
  if (r0 + 25 >= 96)
    for (int i = tid; i < 48; i += 256) *(uint4*)&cells[(25 * 100 + 2 + i * 2) * 4] = z4;
  const bf16* op = og + (size_t)(b * 512 + c * 4) * HW;
  for (int u = tid; u < 26 * 48; u += 256) {
    int rr = u / 48, pr = u - rr * 48;
    int gr = r0 + rr;
    if (gr >= 0 && gr < 96) {
      int gp = gr * 96 + pr * 2;
      unsigned int A = *(const unsigned int*)(op + gp);
      unsigned int B = *(const unsigned int*)(op + HW + gp);
      unsigned int C = *(const unsigned int*)(op + 2 * HW + gp);
      unsigned int D = *(const unsigned int*)(op + (size_t)3 * HW + gp);
      uint4 w;
      w.x = (A & 0xffffu) | (B << 16);          // px0: ch0|ch1
      w.y = (C & 0xffffu) | (D << 16);          // px0: ch2|ch3
      w.z = (A >> 16) | (B & 0xffff0000u);      // px1: ch0|ch1
      w.w = (C >> 16) | (D & 0xffff0000u);      // px1: ch2|ch3
      *(uint4*)&cells[(rr * 100 + 2 + pr * 2) * 4] = w;
    }
  }
  __syncthreads();
  const float* wrow = wf + c * 36;      // uniform -> s_load
  float bias = bfu[c];
  float* outp = out + (size_t)(b * CC + c) * HW + tile * 24 * 96;
#pragma unroll
  for (int pi = 0; pi < 9; ++pi) {
    int p = pi * 256 + tid;
    int ry = p / 96, x = p - ry * 96;
    float a0 = bias, a1 = 0.f, a2 = 0.f, a3 = 0.f;
#pragma unroll
    for (int ky = 0; ky < 3; ++ky) {
      int basec = (ry + ky) * 100 + 1 + x;
#pragma unroll
      for (int kx = 0; kx < 3; ++kx) {
        uint2 cc2 = *(const uint2*)&cells[(basec + kx) * 4];   // b64, 2 lanes/bank
        a0 = fmaf(wrow[0 + ky * 3 + kx],  lo2f(cc2.x), a0);
        a1 = fmaf(wrow[9 + ky * 3 + kx],  hi2f(cc2.x), a1);
        a2 = fmaf(wrow[18 + ky * 3 + kx], lo2f(cc2.y), a2);
        a3 = fmaf(wrow[27 + ky * 3 + kx], hi2f(cc2.y), a3);
      }
    }
    outp[p] = (a0 + a1) + (a2 + a3);
  }
}

// ---------------------------------------------------------------- launcher
extern "C" void kernel_launch(void* const* d_in, const int* in_sizes, int n_in,
                              void* d_out, int out_size, void* d_ws, size_t ws_size,
                              hipStream_t stream) {
  (void)in_sizes; (void)n_in; (void)out_size; (void)ws_size;
  const float* x   = (const float*)d_in[0];
  const float* wq  = (const float*)d_in[1];
  const float* bq  = (const float*)d_in[2];
  const float* tt  = (const float*)d_in[3];
  const float* wf  = (const float*)d_in[4];
  const float* bfu = (const float*)d_in[5];

  // workspace layout (~245 MB)
  char* ws = (char*)d_ws;
  bf16*  qg    = (bf16*)(ws + 0);                 // 75497472 B, later aliased by og
  bf16*  kg    = (bf16*)(ws + 75497472);          // 75497472 B
  bf16*  vg    = (bf16*)(ws + 150994944);         // 75497472 B
  float* part  = (float*)(ws + 226492416);        // 16777216 B
  bf16*  ah    = (bf16*)(ws + 243269632);         // 524288 B
  bf16*  al    = (bf16*)(ws + 243793920);         // 524288 B
  float* qn2   = (float*)(ws + 244318208);        // 16384 B
  float* kn2   = (float*)(ws + 244334592);        // 16384 B
  bf16*  og    = qg;                              // q is dead after k2_gram
  float* out   = (float*)d_out;

  hipLaunchKernelGGL(k1_qkv, dim3(1024), dim3(256), 0, stream,
                     x, wq, bq, qg, kg, vg, qn2, kn2);
  hipLaunchKernelGGL(k2_gram, dim3(NCH, 64), dim3(256), 0, stream, qg, kg, part);
  hipLaunchKernelGGL(k2_softmax, dim3(64, 4), dim3(256), 0, stream,
                     part, ah, al, qn2, kn2, tt);
  hipLaunchKernelGGL(k3_av, dim3(36, 64), dim3(256), 0, stream, ah, al, vg, og);
  hipLaunchKernelGGL(k4_fuse, dim3(4, 1024), dim3(256), 0, stream, og, wf, bfu, out);
}